// Round 6
// baseline (604.720 us; speedup 1.0000x reference)
//
#include <hip/hip_runtime.h>

// CRF (Viterbi + partition + NLL) B=512, S=2048, L=17. Serial-scan problem:
// 1024 chains on 1024 SIMDs, wall = 2048 x per-step issue+stall.
//
// Round-4 counters: fwd 431us, VALUBusy 49% (~250cy issue + ~240 stall per
// step); argmax eq-scan + bp LDS writes are fat in the serial loop.
// This design: forward stores z_t (17 f32) + m_t (17 f32, pre-x max; dup
// lanes 17..33 hold exactly these) to a 144B/row global ring (151MB ws,
// L3-resident); no bp, no index math (~55 insts/step). Backtrace RECOMPUTES
// bp[t][lab]: p_i = z_{t-1,i}+A[i][lab] is bit-identical to fwd's p_i; target
// m_t[lab] via v_readlane(ring,17+lab) (uniform dynamic lane); first-set-bit
// of ballot(p==tgt)&0x1FFFF == first-max-wins. A[.][lab] by uniform-lab
// cndmask bit-tree. 8-deep static-index row prefetch rings BOTH directions;
// forward ring depth 8 (not 4): at ~120cy/step a 4-step lead (~480cy) is
// below L3/HBM latency and the refill waitcnt would become the pole.
// nll gather fused into partition blocks; 2 launches total.
// Fallback (ws too small): round-4 proven path.

constexpr int NL = 17;
constexpr int NS = 2048;
constexpr int NB = 512;
constexpr int ZROW = 36;  // 17 z + 17 m + 2 pad floats = 144 B/row

#define LOG2EF 1.4426950408889634f

__device__ __forceinline__ float readlane_f(float v, int l) {
  return __int_as_float(__builtin_amdgcn_readlane(__float_as_int(v), l));
}
__device__ __forceinline__ float fmax3(float a, float b, float c) {
  return fmaxf(fmaxf(a, b), c);  // v_max3_f32
}

// ======================= fused main kernel =======================
__global__ __launch_bounds__(64, 1) void crf_fused_kernel(
    const float* __restrict__ x, const int* __restrict__ y,
    const float* __restrict__ A, float* __restrict__ preds,
    float* __restrict__ zm, double* __restrict__ wsP) {
  __shared__ unsigned char labs[NS + 72];
  const int bid = blockIdx.x;
  const int lane = threadIdx.x;
  const int j = lane % NL;  // lanes 17..63: dup of j=lane%17

  if (bid < NB) {
    // ---------------- Viterbi forward (no index tracking) ----------------
    const float* xb = x + (size_t)bid * (NS * NL);
    float* zmb = zm + (size_t)bid * ((size_t)NS * ZROW);
    float a[NL];
#pragma unroll
    for (int i = 0; i < NL; ++i) a[i] = A[i * NL + j];
    const bool lt17 = (lane < 17);
    const int zslot = (lane < 34) ? lane : 34;  // z:0..16, m:17..33, junk:34

    float cur = xb[j];  // z_0 = x[:,0,:]
    zmb[zslot] = cur;   // row 0 (m slots unused for t=0)
    float* zp = zmb + ZROW + zslot;      // store cursor, row 1
    const float* xpf = xb + 9 * NL + j;  // refill cursor (t=9), 8-deep lead

    float xq0 = xb[1 * NL + j];
    float xq1 = xb[2 * NL + j];
    float xq2 = xb[3 * NL + j];
    float xq3 = xb[4 * NL + j];
    float xq4 = xb[5 * NL + j];
    float xq5 = xb[6 * NL + j];
    float xq6 = xb[7 * NL + j];
    float xq7 = xb[8 * NL + j];

    auto vstep = [&](float& xr) {
      float p[NL];
#pragma unroll
      for (int i = 0; i < NL; ++i) p[i] = readlane_f(cur, i) + a[i];
      float m0 = fmax3(p[0], p[1], p[2]);
      float m1 = fmax3(p[3], p[4], p[5]);
      float m2 = fmax3(p[6], p[7], p[8]);
      float m3 = fmax3(p[9], p[10], p[11]);
      float m4 = fmax3(p[12], p[13], p[14]);
      float m5 = fmaxf(p[15], p[16]);
      float m = fmaxf(fmax3(m0, m1, m2), fmax3(m3, m4, m5));
      cur = m + xr;          // same fp32 ops as reference (exact)
      *zp = lt17 ? cur : m;  // lanes 17..33 store their own m[j-17] == m[j]
      zp += ZROW;
      xr = *xpf;  // refill ring, 8 steps ahead
      xpf += NL;
    };
    for (int g = 0; g < 254; ++g) {  // steps 1..2032, straight-line addressing
      vstep(xq0); vstep(xq1); vstep(xq2); vstep(xq3);
      vstep(xq4); vstep(xq5); vstep(xq6); vstep(xq7);
    }
    auto vstep_t = [&](float& xr, int t) {  // tail, clamped refill
      float p[NL];
#pragma unroll
      for (int i = 0; i < NL; ++i) p[i] = readlane_f(cur, i) + a[i];
      float m0 = fmax3(p[0], p[1], p[2]);
      float m1 = fmax3(p[3], p[4], p[5]);
      float m2 = fmax3(p[6], p[7], p[8]);
      float m3 = fmax3(p[9], p[10], p[11]);
      float m4 = fmax3(p[12], p[13], p[14]);
      float m5 = fmaxf(p[15], p[16]);
      float m = fmaxf(fmax3(m0, m1, m2), fmax3(m3, m4, m5));
      cur = m + xr;
      *zp = lt17 ? cur : m;
      zp += ZROW;
      int tn = (t + 8 <= NS - 1) ? (t + 8) : (NS - 1);
      xr = xb[tn * NL + j];  // clamped dup loads; never past this batch's x
    };
    // steps 2033..2047 (ring phase: (t-1)&7)
    vstep_t(xq0, 2033); vstep_t(xq1, 2034); vstep_t(xq2, 2035);
    vstep_t(xq3, 2036); vstep_t(xq4, 2037); vstep_t(xq5, 2038);
    vstep_t(xq6, 2039); vstep_t(xq7, 2040); vstep_t(xq0, 2041);
    vstep_t(xq1, 2042); vstep_t(xq2, 2043); vstep_t(xq3, 2044);
    vstep_t(xq4, 2045); vstep_t(xq5, 2046); vstep_t(xq6, 2047);

    // final label: first argmax over z_{NS-1} (lanes 0..16 hold it)
    float bv = readlane_f(cur, 0);
    int bl = 0;
#pragma unroll
    for (int i = 1; i < NL; ++i) {
      float v = readlane_f(cur, i);
      if (v > bv) { bv = v; bl = i; }
    }
    labs[(lane == 0) ? (NS - 1) : (NS + lane)] = (unsigned char)bl;

    // ---------------- backtrace via recompute ----------------
    asm volatile("s_waitcnt vmcnt(0)" ::: "memory");  // fwd stores -> L2
    float aT[NL];  // lane i holds A[i][0..16]
#pragma unroll
    for (int c = 0; c < NL; ++c) aT[c] = A[j * NL + c];
    // ring slots: slot(r) = r & 7 ; init rows 2040..2047
    float r0 = zmb[(size_t)2040 * ZROW + zslot];
    float r1 = zmb[(size_t)2041 * ZROW + zslot];
    float r2 = zmb[(size_t)2042 * ZROW + zslot];
    float r3 = zmb[(size_t)2043 * ZROW + zslot];
    float r4 = zmb[(size_t)2044 * ZROW + zslot];
    float r5 = zmb[(size_t)2045 * ZROW + zslot];
    float r6 = zmb[(size_t)2046 * ZROW + zslot];
    float r7 = zmb[(size_t)2047 * ZROW + zslot];
    const float* rp = zmb + (size_t)2039 * ZROW + zslot;  // next prefetch row
    int lab = bl;

    auto bt_iter = [&](float& rM, float rZ, int t, bool pf) {
      float tgt = readlane_f(rM, 17 + lab);  // m_t[lab] (uniform dyn lane)
      // uniform select asel = aT[lab] (cndmask bit-tree; SALU masks parallel)
      float s0 = (lab & 1) ? aT[1] : aT[0];
      float s1 = (lab & 1) ? aT[3] : aT[2];
      float s2 = (lab & 1) ? aT[5] : aT[4];
      float s3 = (lab & 1) ? aT[7] : aT[6];
      float s4 = (lab & 1) ? aT[9] : aT[8];
      float s5 = (lab & 1) ? aT[11] : aT[10];
      float s6 = (lab & 1) ? aT[13] : aT[12];
      float s7 = (lab & 1) ? aT[15] : aT[14];
      float u0 = (lab & 2) ? s1 : s0;
      float u1 = (lab & 2) ? s3 : s2;
      float u2 = (lab & 2) ? s5 : s4;
      float u3 = (lab & 2) ? s7 : s6;
      float v0 = (lab & 4) ? u1 : u0;
      float v1 = (lab & 4) ? u3 : u2;
      float w0 = (lab & 8) ? v1 : v0;
      float asel = (lab & 16) ? aT[16] : w0;
      float pv = rZ + asel;  // bit-identical to fwd's p_i
      unsigned long long mm = __ballot(pv == tgt) & 0x1FFFFull;
      lab = __ffsll(mm) - 1;  // first set bit = first-max-wins
      labs[(lane == 0) ? (t - 1) : (NS + lane)] = (unsigned char)lab;
      if (pf) { rM = *rp; rp -= ZROW; }  // reuse freed slot, 7-iter lead
    };
    int t0 = 2047;
    for (int g = 0; g < 255; ++g, t0 -= 8) {  // t = 2047 .. 8
      bt_iter(r7, r6, t0 - 0, true);
      bt_iter(r6, r5, t0 - 1, true);
      bt_iter(r5, r4, t0 - 2, true);
      bt_iter(r4, r3, t0 - 3, true);
      bt_iter(r3, r2, t0 - 4, true);
      bt_iter(r2, r1, t0 - 5, true);
      bt_iter(r1, r0, t0 - 6, true);
      bt_iter(r0, r7, t0 - 7, true);
    }
    bt_iter(r7, r6, 7, false);  // rows 0..7 resident
    bt_iter(r6, r5, 6, false);
    bt_iter(r5, r4, 5, false);
    bt_iter(r4, r3, 4, false);
    bt_iter(r3, r2, 3, false);
    bt_iter(r2, r1, 2, false);
    bt_iter(r1, r0, 1, false);

    float* pb = preds + (size_t)bid * NS;
    for (int k = lane; k < NS; k += 64) pb[k] = (float)labs[k];
  } else {
    // ---------------- partition (log-Z) + fused nll gather ----------------
    const int b = bid - NB;
    const float* xb = x + (size_t)b * (NS * NL);
    float E[NL];
#pragma unroll
    for (int i = 0; i < NL; ++i)
      E[i] = __builtin_amdgcn_exp2f(A[i * NL + j] * LOG2EF);  // e^A_ij

    float g = __builtin_amdgcn_exp2f(xb[j] * LOG2EF);
    double base = 0.0;  // accumulated w0 (log2 domain)
    float xr0 = xb[1 * NL + j] * LOG2EF;
    float xr1 = xb[2 * NL + j] * LOG2EF;
    float xr2 = xb[3 * NL + j] * LOG2EF;
    float xr3 = xb[4 * NL + j] * LOG2EF;

    auto pstep = [&](float& xr, int t) {
      float gg[NL];
#pragma unroll
      for (int i = 0; i < NL; ++i) gg[i] = readlane_f(g, i);
      float s0 = gg[0] * E[0];
      float s1 = gg[1] * E[1];
      float s2 = gg[2] * E[2];
      float s3 = gg[3] * E[3];
#pragma unroll
      for (int i = 4; i + 3 < NL; i += 4) {
        s0 = fmaf(gg[i + 0], E[i + 0], s0);
        s1 = fmaf(gg[i + 1], E[i + 1], s1);
        s2 = fmaf(gg[i + 2], E[i + 2], s2);
        s3 = fmaf(gg[i + 3], E[i + 3], s3);
      }
      s0 = fmaf(gg[16], E[16], s0);
      float s = (s0 + s1) + (s2 + s3);
      float w = __builtin_amdgcn_logf(s) + xr;  // log2(s) + x*log2e
      float w0 = readlane_f(w, 0);              // current-step normalizer
      base += (double)w0;
      g = __builtin_amdgcn_exp2f(w - w0);
      int tn = t + 4;
      tn = (tn <= NS - 1) ? tn : (NS - 1);
      xr = xb[tn * NL + j] * LOG2EF;
    };
    for (int tb = 1; tb + 3 < NS; tb += 4) {
      pstep(xr0, tb); pstep(xr1, tb + 1); pstep(xr2, tb + 2); pstep(xr3, tb + 3);
    }
    pstep(xr0, NS - 3); pstep(xr1, NS - 2); pstep(xr2, NS - 1);

    float sg = readlane_f(g, 0);
#pragma unroll
    for (int i = 1; i < NL; ++i) sg += readlane_f(g, i);
    double Zd = (base + (double)__builtin_amdgcn_logf(sg)) * 0.6931471805599453;

    // fused emis+trans gather (this wave has slack vs the Viterbi pole)
    const int* yb = y + (size_t)b * NS;
    float gsum = 0.f;
    for (int it = 0; it < 32; ++it) {
      int t = it * 64 + lane;
      int yt = yb[t];
      int tp = (t >= 1) ? (t - 1) : 0;
      int yp = yb[tp];
      float e = xb[t * NL + yt];
      float tr = (t >= 1) ? A[yt * NL + yp] : 0.0f;
      gsum += e + tr;
    }
#pragma unroll
    for (int off = 32; off >= 1; off >>= 1) gsum += __shfl_xor(gsum, off);
    if (lane == 0) wsP[b] = Zd - (double)gsum;  // -(emis+trans) + Z
  }
}

__global__ __launch_bounds__(512, 1) void crf_mean_kernel(
    const double* __restrict__ wsP, float* __restrict__ outNll) {
  __shared__ double sm[NB];
  const int i = threadIdx.x;
  sm[i] = wsP[i];
  __syncthreads();
  for (int off = NB / 2; off >= 1; off >>= 1) {
    if (i < off) sm[i] += sm[i + off];
    __syncthreads();
  }
  if (i == 0) outNll[0] = (float)(sm[0] * (1.0 / NB));
}

// ================= fallback path (round-4, proven) =================
__global__ __launch_bounds__(64, 1) void crf_fwd_fb(
    const float* __restrict__ x, const float* __restrict__ A,
    float* __restrict__ preds, double* __restrict__ wsZ) {
  __shared__ unsigned char bp[NS * NL + 128];
  __shared__ unsigned char labs[NS + 72];
  const int bid = blockIdx.x;
  const int lane = threadIdx.x;
  const int j = lane % NL;
  if (bid < NB) {
    const float* xb = x + (size_t)bid * (NS * NL);
    float a[NL];
#pragma unroll
    for (int i = 0; i < NL; ++i) a[i] = A[i * NL + j];
    const bool wr = (lane < NL);
    int bpa = wr ? (NL + lane) : (NS * NL + lane);
    const int bps4 = wr ? 4 * NL : 0;
    float cur = xb[j];
    float xr0 = xb[1 * NL + j], xr1 = xb[2 * NL + j];
    float xr2 = xb[3 * NL + j], xr3 = xb[4 * NL + j];
    auto vstep = [&](float& xr, int t, int off) {
      float p[NL];
#pragma unroll
      for (int i = 0; i < NL; ++i) p[i] = readlane_f(cur, i) + a[i];
      float m0 = fmax3(p[0], p[1], p[2]), m1 = fmax3(p[3], p[4], p[5]);
      float m2 = fmax3(p[6], p[7], p[8]), m3 = fmax3(p[9], p[10], p[11]);
      float m4 = fmax3(p[12], p[13], p[14]), m5 = fmaxf(p[15], p[16]);
      float m = fmaxf(fmax3(m0, m1, m2), fmax3(m3, m4, m5));
      cur = m + xr;
      int bi = 16;
#pragma unroll
      for (int k = 15; k >= 0; --k) bi = (p[k] == m) ? k : bi;
      bp[bpa + off] = (unsigned char)bi;
      int tn = t + 4;
      tn = (tn <= NS - 1) ? tn : (NS - 1);
      xr = xb[tn * NL + j];
    };
    for (int tb = 1; tb + 3 < NS; tb += 4) {
      vstep(xr0, tb, 0); vstep(xr1, tb + 1, NL);
      vstep(xr2, tb + 2, 2 * NL); vstep(xr3, tb + 3, 3 * NL);
      bpa += bps4;
    }
    vstep(xr0, NS - 3, 0); vstep(xr1, NS - 2, NL); vstep(xr2, NS - 1, 2 * NL);
    float bv = readlane_f(cur, 0);
    int bl = 0;
#pragma unroll
    for (int i = 1; i < NL; ++i) {
      float v = readlane_f(cur, i);
      if (v > bv) { bv = v; bl = i; }
    }
    const int labsDummy = NS + lane;
    int lab = bl;
    labs[(lane == 0) ? (NS - 1) : labsDummy] = (unsigned char)lab;
    int rr0 = bp[(NS - 1) * NL + j], rr1 = bp[(NS - 2) * NL + j];
    int rr2 = bp[(NS - 3) * NL + j], rr3 = bp[(NS - 4) * NL + j];
    for (int tb = NS - 1; tb >= 4; tb -= 4) {
      int pt;
      lab = __builtin_amdgcn_readlane(rr0, lab);
      labs[(lane == 0) ? (tb - 1) : labsDummy] = (unsigned char)lab;
      pt = tb - 4; rr0 = bp[(pt >= 1 ? pt : 1) * NL + j];
      lab = __builtin_amdgcn_readlane(rr1, lab);
      labs[(lane == 0) ? (tb - 2) : labsDummy] = (unsigned char)lab;
      pt = tb - 5; rr1 = bp[(pt >= 1 ? pt : 1) * NL + j];
      lab = __builtin_amdgcn_readlane(rr2, lab);
      labs[(lane == 0) ? (tb - 3) : labsDummy] = (unsigned char)lab;
      pt = tb - 6; rr2 = bp[(pt >= 1 ? pt : 1) * NL + j];
      lab = __builtin_amdgcn_readlane(rr3, lab);
      labs[(lane == 0) ? (tb - 4) : labsDummy] = (unsigned char)lab;
      pt = tb - 7; rr3 = bp[(pt >= 1 ? pt : 1) * NL + j];
    }
    lab = __builtin_amdgcn_readlane(rr0, lab);
    labs[(lane == 0) ? 2 : labsDummy] = (unsigned char)lab;
    lab = __builtin_amdgcn_readlane(rr1, lab);
    labs[(lane == 0) ? 1 : labsDummy] = (unsigned char)lab;
    lab = __builtin_amdgcn_readlane(rr2, lab);
    labs[(lane == 0) ? 0 : labsDummy] = (unsigned char)lab;
    float* pb = preds + (size_t)bid * NS;
    for (int k = lane; k < NS; k += 64) pb[k] = (float)labs[k];
  } else {
    const int b = bid - NB;
    const float* xb = x + (size_t)b * (NS * NL);
    float E[NL];
#pragma unroll
    for (int i = 0; i < NL; ++i)
      E[i] = __builtin_amdgcn_exp2f(A[i * NL + j] * LOG2EF);
    float g = __builtin_amdgcn_exp2f(xb[j] * LOG2EF);
    double base = 0.0;
    float xr0 = xb[1 * NL + j] * LOG2EF, xr1 = xb[2 * NL + j] * LOG2EF;
    float xr2 = xb[3 * NL + j] * LOG2EF, xr3 = xb[4 * NL + j] * LOG2EF;
    auto pstep = [&](float& xr, int t) {
      float gg[NL];
#pragma unroll
      for (int i = 0; i < NL; ++i) gg[i] = readlane_f(g, i);
      float s0 = gg[0] * E[0], s1 = gg[1] * E[1];
      float s2 = gg[2] * E[2], s3 = gg[3] * E[3];
#pragma unroll
      for (int i = 4; i + 3 < NL; i += 4) {
        s0 = fmaf(gg[i + 0], E[i + 0], s0);
        s1 = fmaf(gg[i + 1], E[i + 1], s1);
        s2 = fmaf(gg[i + 2], E[i + 2], s2);
        s3 = fmaf(gg[i + 3], E[i + 3], s3);
      }
      s0 = fmaf(gg[16], E[16], s0);
      float s = (s0 + s1) + (s2 + s3);
      float w = __builtin_amdgcn_logf(s) + xr;
      float w0 = readlane_f(w, 0);
      base += (double)w0;
      g = __builtin_amdgcn_exp2f(w - w0);
      int tn = t + 4;
      tn = (tn <= NS - 1) ? tn : (NS - 1);
      xr = xb[tn * NL + j] * LOG2EF;
    };
    for (int tb = 1; tb + 3 < NS; tb += 4) {
      pstep(xr0, tb); pstep(xr1, tb + 1); pstep(xr2, tb + 2); pstep(xr3, tb + 3);
    }
    pstep(xr0, NS - 3); pstep(xr1, NS - 2); pstep(xr2, NS - 1);
    float sg = readlane_f(g, 0);
#pragma unroll
    for (int i = 1; i < NL; ++i) sg += readlane_f(g, i);
    if (lane == 0)
      wsZ[b] = (base + (double)__builtin_amdgcn_logf(sg)) * 0.6931471805599453;
  }
}

__global__ __launch_bounds__(64, 1) void crf_gather_fb(
    const float* __restrict__ x, const int* __restrict__ y,
    const float* __restrict__ A, float* __restrict__ wsS) {
  const int bq = blockIdx.x;
  const int b = bq >> 2, q = bq & 3;
  const int lane = threadIdx.x;
  const float* xb = x + (size_t)b * (NS * NL);
  const int* yb = y + (size_t)b * NS;
  const int t0 = q * 512;
  float sum = 0.f;
#pragma unroll
  for (int it = 0; it < 8; ++it) {
    int t = t0 + it * 64 + lane;
    int yt = yb[t];
    sum += xb[t * NL + yt];
    if (t >= 1) sum += A[yt * NL + yb[t - 1]];
  }
#pragma unroll
  for (int off = 32; off >= 1; off >>= 1) sum += __shfl_xor(sum, off);
  if (lane == 0) wsS[bq] = sum;
}

__global__ __launch_bounds__(512, 1) void crf_final_fb(
    const double* __restrict__ wsZ, const float* __restrict__ wsS,
    float* __restrict__ outNll) {
  __shared__ double sm[NB];
  const int b = threadIdx.x;
  float s = (wsS[4 * b] + wsS[4 * b + 1]) + (wsS[4 * b + 2] + wsS[4 * b + 3]);
  sm[b] = wsZ[b] - (double)s;
  __syncthreads();
  for (int off = NB / 2; off >= 1; off >>= 1) {
    if (b < off) sm[b] += sm[b + off];
    __syncthreads();
  }
  if (b == 0) outNll[0] = (float)(sm[0] * (1.0 / NB));
}

extern "C" void kernel_launch(void* const* d_in, const int* in_sizes, int n_in,
                              void* d_out, int out_size, void* d_ws,
                              size_t ws_size, hipStream_t stream) {
  const float* x = (const float*)d_in[0];
  const int* y = (const int*)d_in[1];
  const float* A = (const float*)d_in[2];
  float* out = (float*)d_out;

  const size_t need = 4096 + (size_t)NB * NS * ZROW * sizeof(float);
  if (ws_size >= need) {
    double* wsP = (double*)d_ws;               // [512]
    float* zm = (float*)((char*)d_ws + 4096);  // [512][2048][36]
    crf_fused_kernel<<<dim3(2 * NB), dim3(64), 0, stream>>>(x, y, A, out, zm,
                                                            wsP);
    crf_mean_kernel<<<dim3(1), dim3(512), 0, stream>>>(wsP,
                                                       out + (size_t)NB * NS);
  } else {  // proven round-4 path
    double* wsZ = (double*)d_ws;
    float* wsS = (float*)((char*)d_ws + NB * sizeof(double));
    crf_fwd_fb<<<dim3(2 * NB), dim3(64), 0, stream>>>(x, A, out, wsZ);
    crf_gather_fb<<<dim3(4 * NB), dim3(64), 0, stream>>>(x, y, A, wsS);
    crf_final_fb<<<dim3(1), dim3(512), 0, stream>>>(wsZ, wsS,
                                                    out + (size_t)NB * NS);
  }
}

// Round 7
// 569.452 us; speedup vs baseline: 1.0619x; 1.0619x over previous
//
#include <hip/hip_runtime.h>

// CRF (Viterbi + partition + NLL) B=512, S=2048, L=17.
// Round-6 lesson: recompute-backtrace as a SECOND serial chain stalls on
// HBM reads of the 151MB z+m dump (FETCH ~145MB) -> 536us. But bp[t][j] is
// per-(t,j) INDEPENDENT -- only the byte-chase is serial. New split:
//  K1 (1024x64): blocks<512 lean Viterbi fwd, z-only dump (72B/row, 71MB,
//     ~50 insts/step, no index math, no LDS); blocks>=512 partition+gather
//     (proven exact since r2).
//  K2 (512x512): 8 waves/block compute all 2047 bp rows IN PARALLEL from the
//     z dump (rows independent -> 4 waves/SIMD hide latency; eq-scan is
//     bit-identical to fwd: same inputs, same add), bp bytes -> LDS; wave 0
//     runs the proven LDS readlane byte-chase; 512 threads dump preds.
//  K3: mean.
// Exactness: z stored verbatim fp32; p_i = z+A same op order; first-max-wins
// eq-scan proven in r4 (absmax 0). Clamped dup rows are same-value races.

constexpr int NL = 17;
constexpr int NS = 2048;
constexpr int NB = 512;
constexpr int ZR = 18;  // z row stride (17 + 1 junk slot)

#define LOG2EF 1.4426950408889634f

__device__ __forceinline__ float readlane_f(float v, int l) {
  return __int_as_float(__builtin_amdgcn_readlane(__float_as_int(v), l));
}
__device__ __forceinline__ float fmax3(float a, float b, float c) {
  return fmaxf(fmaxf(a, b), c);  // v_max3_f32
}

// ===================== K1: forward scans =====================
__global__ __launch_bounds__(64, 1) void crf_fwd2_kernel(
    const float* __restrict__ x, const int* __restrict__ y,
    const float* __restrict__ A, float* __restrict__ zws,
    double* __restrict__ wsP) {
  const int bid = blockIdx.x;
  const int lane = threadIdx.x;
  const int j = lane % NL;  // lanes 17..63: harmless dups

  if (bid < NB) {
    // -------- Viterbi forward: value chain only, dump z rows --------
    const float* xb = x + (size_t)bid * (NS * NL);
    float* zb = zws + (size_t)bid * ((size_t)NS * ZR);
    float a[NL];
#pragma unroll
    for (int i = 0; i < NL; ++i) a[i] = A[i * NL + j];
    const int zslot = (lane < 17) ? lane : 17;  // 17 = junk slot

    float cur = xb[j];  // z_0 = x[:,0,:]
    zb[zslot] = cur;    // row 0
    float* zp = zb + ZR + zslot;         // store cursor (row 1)
    const float* xpf = xb + 9 * NL + j;  // refill cursor, 8-deep lead

    float xq0 = xb[1 * NL + j];
    float xq1 = xb[2 * NL + j];
    float xq2 = xb[3 * NL + j];
    float xq3 = xb[4 * NL + j];
    float xq4 = xb[5 * NL + j];
    float xq5 = xb[6 * NL + j];
    float xq6 = xb[7 * NL + j];
    float xq7 = xb[8 * NL + j];

    auto vstep = [&](float& xr) {
      float p[NL];
#pragma unroll
      for (int i = 0; i < NL; ++i) p[i] = readlane_f(cur, i) + a[i];
      float m0 = fmax3(p[0], p[1], p[2]);
      float m1 = fmax3(p[3], p[4], p[5]);
      float m2 = fmax3(p[6], p[7], p[8]);
      float m3 = fmax3(p[9], p[10], p[11]);
      float m4 = fmax3(p[12], p[13], p[14]);
      float m5 = fmaxf(p[15], p[16]);
      float m = fmaxf(fmax3(m0, m1, m2), fmax3(m3, m4, m5));
      cur = m + xr;  // same fp32 ops as reference (exact)
      *zp = cur;     // z dump (junk lanes -> slot 17)
      zp += ZR;
      xr = *xpf;  // ring refill, 8 steps ahead
      xpf += NL;
    };
    for (int g = 0; g < 254; ++g) {  // steps 1..2032
      vstep(xq0); vstep(xq1); vstep(xq2); vstep(xq3);
      vstep(xq4); vstep(xq5); vstep(xq6); vstep(xq7);
    }
    auto vstep_t = [&](float& xr, int t) {  // tail, clamped refill
      float p[NL];
#pragma unroll
      for (int i = 0; i < NL; ++i) p[i] = readlane_f(cur, i) + a[i];
      float m0 = fmax3(p[0], p[1], p[2]);
      float m1 = fmax3(p[3], p[4], p[5]);
      float m2 = fmax3(p[6], p[7], p[8]);
      float m3 = fmax3(p[9], p[10], p[11]);
      float m4 = fmax3(p[12], p[13], p[14]);
      float m5 = fmaxf(p[15], p[16]);
      float m = fmaxf(fmax3(m0, m1, m2), fmax3(m3, m4, m5));
      cur = m + xr;
      *zp = cur;
      zp += ZR;
      int tn = (t + 8 <= NS - 1) ? (t + 8) : (NS - 1);
      xr = xb[tn * NL + j];
    };
    vstep_t(xq0, 2033); vstep_t(xq1, 2034); vstep_t(xq2, 2035);
    vstep_t(xq3, 2036); vstep_t(xq4, 2037); vstep_t(xq5, 2038);
    vstep_t(xq6, 2039); vstep_t(xq7, 2040); vstep_t(xq0, 2041);
    vstep_t(xq1, 2042); vstep_t(xq2, 2043); vstep_t(xq3, 2044);
    vstep_t(xq4, 2045); vstep_t(xq5, 2046); vstep_t(xq6, 2047);
    // done: z rows 0..2047 dumped; K2 does the rest
  } else {
    // -------- partition (log-Z) + fused nll gather (proven) --------
    const int b = bid - NB;
    const float* xb = x + (size_t)b * (NS * NL);
    float E[NL];
#pragma unroll
    for (int i = 0; i < NL; ++i)
      E[i] = __builtin_amdgcn_exp2f(A[i * NL + j] * LOG2EF);  // e^A_ij

    float g = __builtin_amdgcn_exp2f(xb[j] * LOG2EF);
    double base = 0.0;  // accumulated w0 (log2 domain)
    float xr0 = xb[1 * NL + j] * LOG2EF;
    float xr1 = xb[2 * NL + j] * LOG2EF;
    float xr2 = xb[3 * NL + j] * LOG2EF;
    float xr3 = xb[4 * NL + j] * LOG2EF;

    auto pstep = [&](float& xr, int t) {
      float gg[NL];
#pragma unroll
      for (int i = 0; i < NL; ++i) gg[i] = readlane_f(g, i);
      float s0 = gg[0] * E[0];
      float s1 = gg[1] * E[1];
      float s2 = gg[2] * E[2];
      float s3 = gg[3] * E[3];
#pragma unroll
      for (int i = 4; i + 3 < NL; i += 4) {
        s0 = fmaf(gg[i + 0], E[i + 0], s0);
        s1 = fmaf(gg[i + 1], E[i + 1], s1);
        s2 = fmaf(gg[i + 2], E[i + 2], s2);
        s3 = fmaf(gg[i + 3], E[i + 3], s3);
      }
      s0 = fmaf(gg[16], E[16], s0);
      float s = (s0 + s1) + (s2 + s3);
      float w = __builtin_amdgcn_logf(s) + xr;  // log2(s) + x*log2e
      float w0 = readlane_f(w, 0);              // current-step normalizer
      base += (double)w0;
      g = __builtin_amdgcn_exp2f(w - w0);
      int tn = t + 4;
      tn = (tn <= NS - 1) ? tn : (NS - 1);
      xr = xb[tn * NL + j] * LOG2EF;
    };
    for (int tb = 1; tb + 3 < NS; tb += 4) {
      pstep(xr0, tb); pstep(xr1, tb + 1); pstep(xr2, tb + 2); pstep(xr3, tb + 3);
    }
    pstep(xr0, NS - 3); pstep(xr1, NS - 2); pstep(xr2, NS - 1);

    float sg = readlane_f(g, 0);
#pragma unroll
    for (int i = 1; i < NL; ++i) sg += readlane_f(g, i);
    double Zd = (base + (double)__builtin_amdgcn_logf(sg)) * 0.6931471805599453;

    const int* yb = y + (size_t)b * NS;
    float gsum = 0.f;
    for (int it = 0; it < 32; ++it) {
      int t = it * 64 + lane;
      int yt = yb[t];
      int tp = (t >= 1) ? (t - 1) : 0;
      int yp = yb[tp];
      float e = xb[t * NL + yt];
      float tr = (t >= 1) ? A[yt * NL + yp] : 0.0f;
      gsum += e + tr;
    }
#pragma unroll
    for (int off = 32; off >= 1; off >>= 1) gsum += __shfl_xor(gsum, off);
    if (lane == 0) wsP[b] = Zd - (double)gsum;  // -(emis+trans) + Z
  }
}

// ========== K2: parallel bp rows + serial byte-chase + preds ==========
__global__ __launch_bounds__(512, 1) void crf_bt2_kernel(
    const float* __restrict__ zws, const float* __restrict__ A,
    float* __restrict__ preds) {
  __shared__ unsigned char bp[NS * NL + 64];  // rows t=1..2047 + dummy pad
  __shared__ unsigned char labs[NS + 72];
  const int b = blockIdx.x;
  const int tid = threadIdx.x;
  const int lane = tid & 63;
  const int w = tid >> 6;  // wave 0..7
  const int j = lane % NL;
  const float* zb = zws + (size_t)b * ((size_t)NS * ZR);

  float a[NL];
#pragma unroll
  for (int i = 0; i < NL; ++i) a[i] = A[i * NL + j];
  const int zl = (lane < 18) ? lane : 17;
  const bool jok = (lane < 17);
  const int dummyB = NS * NL + lane;  // junk (cross-wave same-addr races ok)

  // wave w owns rows t = 1+w, 1+w+8, ... (256 iters, clamped dups at end)
  int t = 1 + w;
  float zr0 = zb[(size_t)(w + 0) * ZR + zl];
  float zr1 = zb[(size_t)(w + 8) * ZR + zl];
  float zr2 = zb[(size_t)(w + 16) * ZR + zl];
  float zr3 = zb[(size_t)(w + 24) * ZR + zl];
  float zr4 = zb[(size_t)(w + 32) * ZR + zl];
  float zr5 = zb[(size_t)(w + 40) * ZR + zl];
  float zr6 = zb[(size_t)(w + 48) * ZR + zl];
  float zr7 = zb[(size_t)(w + 56) * ZR + zl];

  auto row = [&](float& zr) {
    int trow = (t <= NS - 1) ? t : (NS - 1);
    float p[NL];
#pragma unroll
    for (int i = 0; i < NL; ++i) p[i] = readlane_f(zr, i) + a[i];
    float m0 = fmax3(p[0], p[1], p[2]);
    float m1 = fmax3(p[3], p[4], p[5]);
    float m2 = fmax3(p[6], p[7], p[8]);
    float m3 = fmax3(p[9], p[10], p[11]);
    float m4 = fmax3(p[12], p[13], p[14]);
    float m5 = fmaxf(p[15], p[16]);
    float m = fmaxf(fmax3(m0, m1, m2), fmax3(m3, m4, m5));
    int bi = 16;
#pragma unroll
    for (int k = 15; k >= 0; --k) bi = (p[k] == m) ? k : bi;  // first-max-wins
    bp[jok ? (trow * NL + j) : dummyB] = (unsigned char)bi;
    int nz = t - 1 + 64;  // this slot's next z row (8 iters ahead)
    nz = (nz <= NS - 1) ? nz : (NS - 1);
    zr = zb[(size_t)nz * ZR + zl];
    t += 8;
  };
  for (int g = 0; g < 32; ++g) {
    row(zr0); row(zr1); row(zr2); row(zr3);
    row(zr4); row(zr5); row(zr6); row(zr7);
  }
  __syncthreads();

  if (tid < 64) {
    // final label: first argmax of z_{2047}
    float zf = zb[(size_t)(NS - 1) * ZR + zl];
    float bv = readlane_f(zf, 0);
    int bl = 0;
#pragma unroll
    for (int i = 1; i < NL; ++i) {
      float v = readlane_f(zf, i);
      if (v > bv) { bv = v; bl = i; }
    }
    const int labsDummy = NS + lane;
    int lab = bl;
    labs[(lane == 0) ? (NS - 1) : labsDummy] = (unsigned char)lab;
    int rr0 = bp[(NS - 1) * NL + j];
    int rr1 = bp[(NS - 2) * NL + j];
    int rr2 = bp[(NS - 3) * NL + j];
    int rr3 = bp[(NS - 4) * NL + j];
    for (int tb = NS - 1; tb >= 4; tb -= 4) {
      int pt;
      lab = __builtin_amdgcn_readlane(rr0, lab);
      labs[(lane == 0) ? (tb - 1) : labsDummy] = (unsigned char)lab;
      pt = tb - 4; rr0 = bp[(pt >= 1 ? pt : 1) * NL + j];
      lab = __builtin_amdgcn_readlane(rr1, lab);
      labs[(lane == 0) ? (tb - 2) : labsDummy] = (unsigned char)lab;
      pt = tb - 5; rr1 = bp[(pt >= 1 ? pt : 1) * NL + j];
      lab = __builtin_amdgcn_readlane(rr2, lab);
      labs[(lane == 0) ? (tb - 3) : labsDummy] = (unsigned char)lab;
      pt = tb - 6; rr2 = bp[(pt >= 1 ? pt : 1) * NL + j];
      lab = __builtin_amdgcn_readlane(rr3, lab);
      labs[(lane == 0) ? (tb - 4) : labsDummy] = (unsigned char)lab;
      pt = tb - 7; rr3 = bp[(pt >= 1 ? pt : 1) * NL + j];
    }
    lab = __builtin_amdgcn_readlane(rr0, lab);  // row 3 -> labs[2]
    labs[(lane == 0) ? 2 : labsDummy] = (unsigned char)lab;
    lab = __builtin_amdgcn_readlane(rr1, lab);  // row 2 -> labs[1]
    labs[(lane == 0) ? 1 : labsDummy] = (unsigned char)lab;
    lab = __builtin_amdgcn_readlane(rr2, lab);  // row 1 -> labs[0]
    labs[(lane == 0) ? 0 : labsDummy] = (unsigned char)lab;
  }
  __syncthreads();

  float* pb = preds + (size_t)b * NS;
  for (int k = tid; k < NS; k += 512) pb[k] = (float)labs[k];
}

// ===================== K3: mean =====================
__global__ __launch_bounds__(512, 1) void crf_mean_kernel(
    const double* __restrict__ wsP, float* __restrict__ outNll) {
  __shared__ double sm[NB];
  const int i = threadIdx.x;
  sm[i] = wsP[i];
  __syncthreads();
  for (int off = NB / 2; off >= 1; off >>= 1) {
    if (i < off) sm[i] += sm[i + off];
    __syncthreads();
  }
  if (i == 0) outNll[0] = (float)(sm[0] * (1.0 / NB));
}

extern "C" void kernel_launch(void* const* d_in, const int* in_sizes, int n_in,
                              void* d_out, int out_size, void* d_ws,
                              size_t ws_size, hipStream_t stream) {
  const float* x = (const float*)d_in[0];
  const int* y = (const int*)d_in[1];  // integers delivered as int32
  const float* A = (const float*)d_in[2];
  float* out = (float*)d_out;   // [B*S] preds-as-float, then nll scalar
  double* wsP = (double*)d_ws;  // [512]
  float* zws = (float*)((char*)d_ws + 4096);  // [512][2048][18] = 75.5 MB

  crf_fwd2_kernel<<<dim3(2 * NB), dim3(64), 0, stream>>>(x, y, A, zws, wsP);
  crf_bt2_kernel<<<dim3(NB), dim3(512), 0, stream>>>(zws, A, out);
  crf_mean_kernel<<<dim3(1), dim3(512), 0, stream>>>(wsP,
                                                     out + (size_t)NB * NS);
}